// Round 4
// baseline (323.152 us; speedup 1.0000x reference)
//
#include <hip/hip_runtime.h>
#include <hip/hip_bf16.h>
#include <math.h>

// Problem constants
#define BB 16
#define NN 4096
#define CC 256
#define NC 768     // 3*C
#define MTOT (BB * NN)   // 65536 tokens

typedef __attribute__((ext_vector_type(8))) __bf16 bf16x8;
typedef __attribute__((ext_vector_type(4))) float f32x4;

__device__ __forceinline__ unsigned short f2bf(float f) {
    union { float f; unsigned int u; } v; v.f = f;
    unsigned int r = (v.u + 0x7FFFu + ((v.u >> 16) & 1u)) >> 16;
    return (unsigned short)r;
}
__device__ __forceinline__ float bf2f(unsigned short b) {
    union { unsigned int u; float f; } v; v.u = ((unsigned int)b) << 16;
    return v.f;
}

#define GL16(gp, lp) \
    __builtin_amdgcn_global_load_lds((const __attribute__((address_space(1))) void*)(gp), \
                                     (__attribute__((address_space(3))) void*)(lp), 16, 0, 0)

// ---------------------------------------------------------------------------
// m97-style GEMM core for the tiny weight-prep GEMMs (K=256).  (unchanged)
// ---------------------------------------------------------------------------
template<int KDIM>
__device__ __forceinline__ void gemm_tile(const unsigned short* __restrict__ A,
                                          const unsigned short* __restrict__ Bt,
                                          int bm, int bn,
                                          unsigned short* As, unsigned short* Bs,
                                          f32x4 (&acc)[4][4]) {
    const int tid = threadIdx.x;
    const int lane = tid & 63;
    const int wave = tid >> 6;
    const int q = lane >> 4;
    const int r16 = lane & 15;
    const int wm = (wave >> 1) * 64;
    const int wn = (wave & 1) * 64;

    const int e0 = tid, e1 = tid + 256;
    const int r0 = e0 >> 2, r1 = e1 >> 2;
    const int kc0 = (e0 & 3) ^ ((r0 >> 1) & 3);
    const int kc1 = (e1 & 3) ^ ((r1 >> 1) & 3);
    const unsigned short* gA0 = A + (size_t)(bm + r0) * KDIM + kc0 * 8;
    const unsigned short* gA1 = A + (size_t)(bm + r1) * KDIM + kc1 * 8;
    const unsigned short* gB0 = Bt + (size_t)(bn + r0) * KDIM + kc0 * 8;
    const unsigned short* gB1 = Bt + (size_t)(bn + r1) * KDIM + kc1 * 8;

    const int sw = (q ^ ((r16 >> 1) & 3)) * 8;

    for (int kt = 0; kt < KDIM; kt += 32) {
        if (kt) __syncthreads();
        GL16(gA0 + kt, As + e0 * 8);
        GL16(gA1 + kt, As + e1 * 8);
        GL16(gB0 + kt, Bs + e0 * 8);
        GL16(gB1 + kt, Bs + e1 * 8);
        __syncthreads();

        bf16x8 af[4], bfr[4];
#pragma unroll
        for (int mi = 0; mi < 4; ++mi)
            af[mi] = *(const bf16x8*)(As + (wm + mi * 16 + r16) * 32 + sw);
#pragma unroll
        for (int ni = 0; ni < 4; ++ni)
            bfr[ni] = *(const bf16x8*)(Bs + (wn + ni * 16 + r16) * 32 + sw);
#pragma unroll
        for (int mi = 0; mi < 4; ++mi)
#pragma unroll
            for (int ni = 0; ni < 4; ++ni)
                acc[mi][ni] = __builtin_amdgcn_mfma_f32_16x16x32_bf16(
                    af[mi], bfr[ni], acc[mi][ni], 0, 0, 0);
    }
}

// ---------------------------------------------------------------------------
// Fused converter: Wqkv -> Wqb/Wkb/Wvs (bf16), Wproj -> WpT (bf16 transposed)
// ---------------------------------------------------------------------------
__global__ __launch_bounds__(256) void conv_all(const float* __restrict__ Wqkv,
                                                const float* __restrict__ Wproj,
                                                unsigned short* __restrict__ Wqb,
                                                unsigned short* __restrict__ Wkb,
                                                unsigned short* __restrict__ Wvs,
                                                unsigned short* __restrict__ WpT) {
    int t = blockIdx.x * 256 + threadIdx.x;
    if (t < 3 * CC * NC) {
        unsigned short v = f2bf(Wqkv[t]);
        int ic = t / NC;           // i*256 + a  (input channel a)
        int col = t - ic * NC;
        if (col < 256)       Wqb[(size_t)ic * CC + col] = v;
        else if (col < 512)  Wkb[(size_t)ic * CC + col - 256] = v;
        else                 Wvs[(size_t)ic * CC + col - 512] = v;
    } else {
        int e = t - 3 * CC * NC;   // < 65536
        int g = e >> 8, c = e & 255;
        WpT[e] = f2bf(Wproj[(size_t)c * CC + g]);   // WpT[g][c] = Wproj[c][g]
    }
}

// ---------------------------------------------------------------------------
// Batched weight GEMM: z<3 -> MtY_i = scale * Wk_i Wq_i^T  (256x256)
//                      z=3 -> PtZ = (1/3) * Wproj^T x Wv   (256x768)
// ---------------------------------------------------------------------------
__global__ __launch_bounds__(256) void wgemm(const unsigned short* __restrict__ Wqb,
                                             const unsigned short* __restrict__ Wkb,
                                             const unsigned short* __restrict__ Wvs,
                                             const unsigned short* __restrict__ WpT,
                                             unsigned short* __restrict__ MtY,
                                             unsigned short* __restrict__ PtZ) {
    const int z = blockIdx.z;
    const unsigned short *A, *Bt;
    unsigned short* C;
    int nout; float mult;
    if (z < 3) {
        if (blockIdx.x >= 2) return;
        A = Wkb + z * CC * CC; Bt = Wqb + z * CC * CC; C = MtY + z * CC * CC;
        nout = CC; mult = 0.0625f;            // C^-0.5
    } else {
        A = WpT; Bt = Wvs; C = PtZ;
        nout = NC; mult = 1.0f / 3.0f;
    }

    __shared__ unsigned short As[128 * 32];
    __shared__ unsigned short Bs[128 * 32];
    f32x4 acc[4][4];
#pragma unroll
    for (int i = 0; i < 4; ++i)
#pragma unroll
        for (int j = 0; j < 4; ++j) acc[i][j] = {0.f, 0.f, 0.f, 0.f};

    gemm_tile<CC>(A, Bt, blockIdx.y * 128, blockIdx.x * 128, As, Bs, acc);

    const int lane = threadIdx.x & 63;
    const int wave = threadIdx.x >> 6;
    const int q = lane >> 4, r16 = lane & 15;
    const int wm = (wave >> 1) * 64, wn = (wave & 1) * 64;
#pragma unroll
    for (int mi = 0; mi < 4; ++mi)
#pragma unroll
        for (int ni = 0; ni < 4; ++ni) {
            int row0 = blockIdx.y * 128 + wm + mi * 16 + q * 4;
            int col = blockIdx.x * 128 + wn + ni * 16 + r16;
#pragma unroll
            for (int r = 0; r < 4; ++r)
                C[(size_t)(row0 + r) * nout + col] = f2bf(acc[mi][ni][r] * mult);
        }
}

// ---------------------------------------------------------------------------
// MEGA kernel, v3: N-split waves (zero-duplication weight reads).
//
// v2 was LDS-port-bound: B-frags were re-read by all 4 waves (40KB LDS
// traffic per 8KB stage).  v3: each wave owns 64 OUTPUT channels and all
// 64 tokens, so each staged weight byte is ds_read by exactly one wave
// (P1) / its half-owner (P3).  A-frags (x / z) are read per-slot from
// xbuf / built in regs.
//
// Stage stream: 96 stages x 8KB, ring of 3 (24KB), issued 2 ahead,
//   consume sync = s_waitcnt vmcnt(2) + raw s_barrier (never 0 in loop).
//   M-stages reordered ktp-major (slot = ktp*4+cq) so wave wn (owns cq==wn)
//   finishes its Y columns with full K by slot 12+wn.
// Logits: per-wave partial over its 64 cols via yseg transpose + 6 MFMAs
//   per tokfrag; diag lanes write part[wave][tok][3]; summed by all waves
//   after the per-dilation drain slot; softmax replicated per wave.
// P3: z built in regs per (kt, tokfrag) from xbuf + softmax weights
//   (v_cvt_pk_bf16_f32 pack), 16 MFMAs per owned stage-half.
//
// LDS: xbuf 70x264 (36960) + ring 3x8KB (24576) + yseg 4x16x72 (9216)
//      + part 4x64x3 f32 (3072) = 73824 B -> 2 blocks/CU.
// ---------------------------------------------------------------------------
__global__ __launch_bounds__(256, 2) void mega(const float* __restrict__ xf,
                                               const unsigned short* __restrict__ MtY,
                                               const unsigned short* __restrict__ PtZ,
                                               const float* __restrict__ bias,
                                               float* __restrict__ out) {
    __shared__ __align__(16) unsigned short xbuf[70 * 264];
    __shared__ __align__(16) unsigned short bstage[3 * 4096];
    __shared__ __align__(16) unsigned short yseg[4 * 16 * 72];
    __shared__ __align__(16) float part[4][64][3];

    const int tid = threadIdx.x;
    const int lane = tid & 63;
    const int wn = tid >> 6;          // wave id == owned output quarter
    const int q = lane >> 4;
    const int r16 = lane & 15;
    const int t0 = blockIdx.x * 64;

    // per-thread staging source precompute (conflict swizzle as before)
    const int colA = tid >> 2;
    const int kcA = (tid & 3) ^ ((colA >> 1) & 3);
    const unsigned short* mBase  = MtY + (size_t)colA * CC + kcA * 8;
    const unsigned short* pBase0 = PtZ + (size_t)colA * NC + kcA * 8;
    const unsigned short* pBase1 = PtZ + (size_t)(colA + 64) * NC + kcA * 8;

    // Stage gs (0..95): dil i2 = gs>>5; r = gs&31.
    //  r<16 : M-stage, ktp-major: ktp = r>>2, cq = r&3 (64 cols x 64 k).
    //  r>=16: P-stage: kt = (r-16)>>1, cqp = (r-16)&1 (128 out-cols x 32 k).
    auto issue_stage = [&](int gs) {
        if (gs >= 96) return;
        unsigned short* dst = bstage + (gs % 3) * 4096 + tid * 8;
        const int i2 = gs >> 5;
        const int r = gs & 31;
        if (r < 16) {
            const unsigned short* src =
                mBase + (size_t)(i2 * 256 + (r & 3) * 64) * CC + (r >> 2) * 64;
            GL16(src, dst);                 // kk = 0
            GL16(src + 32, dst + 2048);     // kk = 1
        } else {
            const int r2 = r - 16;
            const size_t off = (size_t)(r2 & 1) * (128 * NC) + i2 * 256 + (r2 >> 1) * 32;
            GL16(pBase0 + off, dst);            // cols 0..63 of the 128-half
            GL16(pBase1 + off, dst + 2048);     // cols 64..127
        }
    };

    // prologue: 2-ahead pipeline starts while x is staged
    issue_stage(0); issue_stage(1);

    // ---- stage x rows [t0-3, t0+67) fp32 -> bf16 LDS (clamped; masked later)
    for (int it = 0; it < 9; ++it) {
        int e = it * 256 + tid;          // 70 rows * 32 chunks = 2240
        if (e < 2240) {
            int rr = e >> 5, c = e & 31;
            int gr = t0 - 3 + rr;
            gr = gr < 0 ? 0 : (gr > MTOT - 1 ? MTOT - 1 : gr);
            const float* xp = xf + (size_t)gr * CC + c * 8;
            float4 a = *(const float4*)xp;
            float4 b = *(const float4*)(xp + 4);
            unsigned short p[8];
            p[0] = f2bf(a.x); p[1] = f2bf(a.y); p[2] = f2bf(a.z); p[3] = f2bf(a.w);
            p[4] = f2bf(b.x); p[5] = f2bf(b.y); p[6] = f2bf(b.z); p[7] = f2bf(b.w);
            *(float4*)(xbuf + rr * 264 + c * 8) = *(const float4*)p;
        }
    }
    __syncthreads();   // drains x loads AND stages 0-1 (one-time vmcnt(0))

    f32x4 oacc[16];    // [tf][nf]: rows tf*16+q*4+r, cols wn*64+nf*16+r16
#pragma unroll
    for (int j = 0; j < 16; ++j) oacc[j] = {0.f, 0.f, 0.f, 0.f};

    const int fragsw = q ^ ((r16 >> 1) & 3);   // fragment k-chunk swizzle
    int sctr = 0;    // consumed-stage counter (issue = sctr + 2)

#pragma unroll 1
    for (int i = 0; i < 3; ++i) {
        const int dil = i + 1;
        f32x4 yacc[16];   // [tf][nf]: Y rows tf*16+q*4+r, cols wn*64+nf*16+r16
#pragma unroll
        for (int j = 0; j < 16; ++j) yacc[j] = {0.f, 0.f, 0.f, 0.f};
        float wgt[4][3];

        // per-wave logit partials over its 64 cols (Y final in yacc)
        auto logit_work = [&]() {
            unsigned short* ys = yseg + wn * (16 * 72);
#pragma unroll
            for (int tf = 0; tf < 4; ++tf) {
#pragma unroll
                for (int nf = 0; nf < 4; ++nf)
#pragma unroll
                    for (int rr = 0; rr < 4; ++rr)
                        ys[(q * 4 + rr) * 72 + nf * 16 + r16] =
                            f2bf(yacc[tf * 4 + nf][rr]);
                asm volatile("s_waitcnt lgkmcnt(0)" ::: "memory");
                __builtin_amdgcn_sched_barrier(0);
                bf16x8 ya0 = *(const bf16x8*)(ys + r16 * 72 + q * 8);
                bf16x8 ya1 = *(const bf16x8*)(ys + r16 * 72 + 32 + q * 8);
                f32x4 lacc[3];
#pragma unroll
                for (int j = 0; j < 3; ++j) lacc[j] = {0.f, 0.f, 0.f, 0.f};
#pragma unroll
                for (int j = 0; j < 3; ++j) {
                    const unsigned short* xr =
                        xbuf + (3 + tf * 16 + r16 + (j - 1) * dil) * 264 + wn * 64 + q * 8;
                    lacc[j] = __builtin_amdgcn_mfma_f32_16x16x32_bf16(
                        ya0, *(const bf16x8*)xr, lacc[j], 0, 0, 0);
                    lacc[j] = __builtin_amdgcn_mfma_f32_16x16x32_bf16(
                        ya1, *(const bf16x8*)(xr + 32), lacc[j], 0, 0, 0);
                }
                if (q == (r16 >> 2)) {       // diag lanes own token tf*16+r16
                    const int rr = r16 & 3;
                    float p0 = rr == 0 ? lacc[0][0] : rr == 1 ? lacc[0][1] : rr == 2 ? lacc[0][2] : lacc[0][3];
                    float p1 = rr == 0 ? lacc[1][0] : rr == 1 ? lacc[1][1] : rr == 2 ? lacc[1][2] : lacc[1][3];
                    float p2 = rr == 0 ? lacc[2][0] : rr == 1 ? lacc[2][1] : rr == 2 ? lacc[2][2] : lacc[2][3];
                    part[wn][tf * 16 + r16][0] = p0;
                    part[wn][tf * 16 + r16][1] = p1;
                    part[wn][tf * 16 + r16][2] = p2;
                }
            }
            asm volatile("s_waitcnt lgkmcnt(0)" ::: "memory");   // publish parts
        };

        // ================= M phase: 16 slots (ktp-major) =================
        for (int sl = 0; sl < 16; ++sl) {
            asm volatile("s_waitcnt vmcnt(2)" ::: "memory");   // stage sctr done
            __builtin_amdgcn_s_barrier();
            __builtin_amdgcn_sched_barrier(0);
            issue_stage(sctr + 2);
            const int ktp = sl >> 2, cq = sl & 3;
            if (cq == wn) {
                const unsigned short* bp = bstage + (sctr % 3) * 4096;
#pragma unroll
                for (int kk = 0; kk < 2; ++kk) {
                    bf16x8 bfr[4], afv[4];
#pragma unroll
                    for (int nf = 0; nf < 4; ++nf)
                        bfr[nf] = *(const bf16x8*)(bp + kk * 2048 +
                                      ((nf * 16 + r16) * 4 + fragsw) * 8);
#pragma unroll
                    for (int tf = 0; tf < 4; ++tf)
                        afv[tf] = *(const bf16x8*)(xbuf + (3 + tf * 16 + r16) * 264 +
                                      ktp * 64 + kk * 32 + q * 8);
                    __builtin_amdgcn_s_setprio(1);
#pragma unroll
                    for (int tf = 0; tf < 4; ++tf)
#pragma unroll
                        for (int nf = 0; nf < 4; ++nf)
                            yacc[tf * 4 + nf] = __builtin_amdgcn_mfma_f32_16x16x32_bf16(
                                afv[tf], bfr[nf], yacc[tf * 4 + nf], 0, 0, 0);
                    __builtin_amdgcn_s_setprio(0);
                }
            }
            // staggered logit slots: wave wn at slot 13+wn (wn<3; wn==3 at drain)
            if (ktp == 3 && wn < 3 && cq == wn + 1) logit_work();
            ++sctr;
        }

        // ================= drain slot: wn==3 logits =================
        __builtin_amdgcn_s_barrier();
        __builtin_amdgcn_sched_barrier(0);
        if (wn == 3) logit_work();

        // ================= P phase: 16 slots =================
        for (int sl = 0; sl < 16; ++sl) {
            asm volatile("s_waitcnt vmcnt(2)" ::: "memory");
            __builtin_amdgcn_s_barrier();
            __builtin_amdgcn_sched_barrier(0);
            issue_stage(sctr + 2);
            const int kt = sl >> 1, cqp = sl & 1;
            if (sl == 0) {
                // combine partials + softmax (replicated per wave; all lanes)
#pragma unroll
                for (int tf = 0; tf < 4; ++tf) {
                    const int tok = tf * 16 + r16;
                    float l0 = part[0][tok][0] + part[1][tok][0] +
                               part[2][tok][0] + part[3][tok][0];
                    float l1 = part[0][tok][1] + part[1][tok][1] +
                               part[2][tok][1] + part[3][tok][1];
                    float l2 = part[0][tok][2] + part[1][tok][2] +
                               part[2][tok][2] + part[3][tok][2];
                    const int ns = (t0 + tok) & (NN - 1);
                    const bool vlo = ns >= dil;
                    const bool vhi = ns + dil < NN;
                    l0 = vlo ? l0 : 0.f;   // zero-logit padding (matches reference)
                    l2 = vhi ? l2 : 0.f;
                    float mx = fmaxf(l0, fmaxf(l1, l2));
                    float e0 = __expf(l0 - mx), e1 = __expf(l1 - mx), e2 = __expf(l2 - mx);
                    float inv = 1.0f / (e0 + e1 + e2);
                    wgt[tf][0] = vlo ? e0 * inv : 0.f;
                    wgt[tf][1] = e1 * inv;
                    wgt[tf][2] = vhi ? e2 * inv : 0.f;
                }
            }
            if (cqp == (wn >> 1)) {
                const unsigned short* bp = bstage + (sctr % 3) * 4096;
                // build z A-frags for this k-slab (all 64 tokens, 4 tokfrags)
                union { unsigned int w[4]; bf16x8 v; } za[4];
#pragma unroll
                for (int tf = 0; tf < 4; ++tf) {
                    const unsigned short* xr1 =
                        xbuf + (3 + tf * 16 + r16) * 264 + kt * 32 + q * 8;
                    bf16x8 a0 = *(const bf16x8*)(xr1 - dil * 264);
                    bf16x8 a1 = *(const bf16x8*)(xr1);
                    bf16x8 a2 = *(const bf16x8*)(xr1 + dil * 264);
                    const unsigned short* u0 = (const unsigned short*)&a0;
                    const unsigned short* u1 = (const unsigned short*)&a1;
                    const unsigned short* u2 = (const unsigned short*)&a2;
                    const float w0 = wgt[tf][0], w1 = wgt[tf][1], w2 = wgt[tf][2];
#pragma unroll
                    for (int e2i = 0; e2i < 4; ++e2i) {
                        float zl = w0 * bf2f(u0[e2i * 2]) + w1 * bf2f(u1[e2i * 2]) +
                                   w2 * bf2f(u2[e2i * 2]);
                        float zh = w0 * bf2f(u0[e2i * 2 + 1]) + w1 * bf2f(u1[e2i * 2 + 1]) +
                                   w2 * bf2f(u2[e2i * 2 + 1]);
                        asm("v_cvt_pk_bf16_f32 %0, %1, %2"
                            : "=v"(za[tf].w[e2i]) : "v"(zl), "v"(zh));
                    }
                }
                __builtin_amdgcn_s_setprio(1);
#pragma unroll
                for (int nf = 0; nf < 4; ++nf) {
                    bf16x8 b = *(const bf16x8*)(bp + (wn & 1) * 2048 +
                                    ((nf * 16 + r16) * 4 + fragsw) * 8);
#pragma unroll
                    for (int tf = 0; tf < 4; ++tf)
                        oacc[tf * 4 + nf] = __builtin_amdgcn_mfma_f32_16x16x32_bf16(
                            za[tf].v, b, oacc[tf * 4 + nf], 0, 0, 0);
                }
                __builtin_amdgcn_s_setprio(0);
            }
            ++sctr;
        }
    }

    // ================= Epilogue: out = oacc + bias =================
#pragma unroll
    for (int tf = 0; tf < 4; ++tf)
#pragma unroll
        for (int nf = 0; nf < 4; ++nf) {
            const int gc = wn * 64 + nf * 16 + r16;
            float bc = bias[gc];
            f32x4 v = oacc[tf * 4 + nf];
#pragma unroll
            for (int r = 0; r < 4; ++r)
                out[(size_t)(t0 + tf * 16 + q * 4 + r) * CC + gc] = v[r] + bc;
        }
}

// ---------------------------------------------------------------------------
extern "C" void kernel_launch(void* const* d_in, const int* in_sizes, int n_in,
                              void* d_out, int out_size, void* d_ws, size_t ws_size,
                              hipStream_t stream) {
    const float* x = (const float*)d_in[0];      // (16, 4096, 256)
    const float* Wqkv = (const float*)d_in[1];   // (3, 256, 768)
    const float* Wproj = (const float*)d_in[2];  // (256, 256)
    const float* bproj = (const float*)d_in[3];  // (256,)
    float* out = (float*)d_out;                  // (16, 4096, 256)

    unsigned short* Wqb = (unsigned short*)d_ws;           // 3*256*256
    unsigned short* Wkb = Wqb + (size_t)3 * CC * CC;
    unsigned short* Wvs = Wkb + (size_t)3 * CC * CC;       // (768,256): [(i,a)][c]
    unsigned short* WpT = Wvs + (size_t)3 * CC * CC;       // (256,256): [g][c]
    unsigned short* MtY = WpT + (size_t)CC * CC;           // (768,256): [(i,b)][a]
    unsigned short* PtZ = MtY + (size_t)NC * CC;           // (256,768): [g][(i,a)]

    conv_all<<<(3 * CC * NC + CC * CC) / 256, 256, 0, stream>>>(
        Wqkv, Wproj, Wqb, Wkb, Wvs, WpT);
    wgemm<<<dim3(6, 2, 4), 256, 0, stream>>>(Wqb, Wkb, Wvs, WpT, MtY, PtZ);
    mega<<<MTOT / 64, 256, 0, stream>>>(x, MtY, PtZ, bproj, out);
}

// Round 6
// 200.041 us; speedup vs baseline: 1.6154x; 1.6154x over previous
//
#include <hip/hip_runtime.h>
#include <hip/hip_bf16.h>
#include <math.h>

// Problem constants
#define BB 16
#define NN 4096
#define CC 256
#define NC 768     // 3*C
#define MTOT (BB * NN)   // 65536 tokens

typedef __attribute__((ext_vector_type(8))) __bf16 bf16x8;
typedef __attribute__((ext_vector_type(4))) float f32x4;

__device__ __forceinline__ unsigned short f2bf(float f) {
    union { float f; unsigned int u; } v; v.f = f;
    unsigned int r = (v.u + 0x7FFFu + ((v.u >> 16) & 1u)) >> 16;
    return (unsigned short)r;
}
__device__ __forceinline__ float bf2f(unsigned short b) {
    union { unsigned int u; float f; } v; v.u = ((unsigned int)b) << 16;
    return v.f;
}

#define GL16(gp, lp) \
    __builtin_amdgcn_global_load_lds((const __attribute__((address_space(1))) void*)(gp), \
                                     (__attribute__((address_space(3))) void*)(lp), 16, 0, 0)

// ---------------------------------------------------------------------------
// m97-style GEMM core for the tiny weight-prep GEMMs (K=256).  (unchanged)
// ---------------------------------------------------------------------------
template<int KDIM>
__device__ __forceinline__ void gemm_tile(const unsigned short* __restrict__ A,
                                          const unsigned short* __restrict__ Bt,
                                          int bm, int bn,
                                          unsigned short* As, unsigned short* Bs,
                                          f32x4 (&acc)[4][4]) {
    const int tid = threadIdx.x;
    const int lane = tid & 63;
    const int wave = tid >> 6;
    const int q = lane >> 4;
    const int r16 = lane & 15;
    const int wm = (wave >> 1) * 64;
    const int wn = (wave & 1) * 64;

    const int e0 = tid, e1 = tid + 256;
    const int r0 = e0 >> 2, r1 = e1 >> 2;
    const int kc0 = (e0 & 3) ^ ((r0 >> 1) & 3);
    const int kc1 = (e1 & 3) ^ ((r1 >> 1) & 3);
    const unsigned short* gA0 = A + (size_t)(bm + r0) * KDIM + kc0 * 8;
    const unsigned short* gA1 = A + (size_t)(bm + r1) * KDIM + kc1 * 8;
    const unsigned short* gB0 = Bt + (size_t)(bn + r0) * KDIM + kc0 * 8;
    const unsigned short* gB1 = Bt + (size_t)(bn + r1) * KDIM + kc1 * 8;

    const int sw = (q ^ ((r16 >> 1) & 3)) * 8;

    for (int kt = 0; kt < KDIM; kt += 32) {
        if (kt) __syncthreads();
        GL16(gA0 + kt, As + e0 * 8);
        GL16(gA1 + kt, As + e1 * 8);
        GL16(gB0 + kt, Bs + e0 * 8);
        GL16(gB1 + kt, Bs + e1 * 8);
        __syncthreads();

        bf16x8 af[4], bfr[4];
#pragma unroll
        for (int mi = 0; mi < 4; ++mi)
            af[mi] = *(const bf16x8*)(As + (wm + mi * 16 + r16) * 32 + sw);
#pragma unroll
        for (int ni = 0; ni < 4; ++ni)
            bfr[ni] = *(const bf16x8*)(Bs + (wn + ni * 16 + r16) * 32 + sw);
#pragma unroll
        for (int mi = 0; mi < 4; ++mi)
#pragma unroll
            for (int ni = 0; ni < 4; ++ni)
                acc[mi][ni] = __builtin_amdgcn_mfma_f32_16x16x32_bf16(
                    af[mi], bfr[ni], acc[mi][ni], 0, 0, 0);
    }
}

// ---------------------------------------------------------------------------
// Fused converter: Wqkv -> Wqb/Wkb/Wvs (bf16), Wproj -> WpT (bf16 transposed)
// ---------------------------------------------------------------------------
__global__ __launch_bounds__(256) void conv_all(const float* __restrict__ Wqkv,
                                                const float* __restrict__ Wproj,
                                                unsigned short* __restrict__ Wqb,
                                                unsigned short* __restrict__ Wkb,
                                                unsigned short* __restrict__ Wvs,
                                                unsigned short* __restrict__ WpT) {
    int t = blockIdx.x * 256 + threadIdx.x;
    if (t < 3 * CC * NC) {
        unsigned short v = f2bf(Wqkv[t]);
        int ic = t / NC;           // i*256 + a  (input channel a)
        int col = t - ic * NC;
        if (col < 256)       Wqb[(size_t)ic * CC + col] = v;
        else if (col < 512)  Wkb[(size_t)ic * CC + col - 256] = v;
        else                 Wvs[(size_t)ic * CC + col - 512] = v;
    } else {
        int e = t - 3 * CC * NC;   // < 65536
        int g = e >> 8, c = e & 255;
        WpT[e] = f2bf(Wproj[(size_t)c * CC + g]);   // WpT[g][c] = Wproj[c][g]
    }
}

// ---------------------------------------------------------------------------
// Batched weight GEMM: z<3 -> MtY_i = scale * Wk_i Wq_i^T  (256x256)
//                      z=3 -> PtZ = (1/3) * Wproj^T x Wv   (256x768)
// ---------------------------------------------------------------------------
__global__ __launch_bounds__(256) void wgemm(const unsigned short* __restrict__ Wqb,
                                             const unsigned short* __restrict__ Wkb,
                                             const unsigned short* __restrict__ Wvs,
                                             const unsigned short* __restrict__ WpT,
                                             unsigned short* __restrict__ MtY,
                                             unsigned short* __restrict__ PtZ) {
    const int z = blockIdx.z;
    const unsigned short *A, *Bt;
    unsigned short* C;
    int nout; float mult;
    if (z < 3) {
        if (blockIdx.x >= 2) return;
        A = Wkb + z * CC * CC; Bt = Wqb + z * CC * CC; C = MtY + z * CC * CC;
        nout = CC; mult = 0.0625f;            // C^-0.5
    } else {
        A = WpT; Bt = Wvs; C = PtZ;
        nout = NC; mult = 1.0f / 3.0f;
    }

    __shared__ unsigned short As[128 * 32];
    __shared__ unsigned short Bs[128 * 32];
    f32x4 acc[4][4];
#pragma unroll
    for (int i = 0; i < 4; ++i)
#pragma unroll
        for (int j = 0; j < 4; ++j) acc[i][j] = {0.f, 0.f, 0.f, 0.f};

    gemm_tile<CC>(A, Bt, blockIdx.y * 128, blockIdx.x * 128, As, Bs, acc);

    const int lane = threadIdx.x & 63;
    const int wave = threadIdx.x >> 6;
    const int q = lane >> 4, r16 = lane & 15;
    const int wm = (wave >> 1) * 64, wn = (wave & 1) * 64;
#pragma unroll
    for (int mi = 0; mi < 4; ++mi)
#pragma unroll
        for (int ni = 0; ni < 4; ++ni) {
            int row0 = blockIdx.y * 128 + wm + mi * 16 + q * 4;
            int col = blockIdx.x * 128 + wn + ni * 16 + r16;
#pragma unroll
            for (int r = 0; r < 4; ++r)
                C[(size_t)(row0 + r) * nout + col] = f2bf(acc[mi][ni][r] * mult);
        }
}

// ---------------------------------------------------------------------------
// MEGA kernel, v4: 2x2 wave split + 16KB super-stages (ring 2, 48 barriers).
//
// Waves = (tg, cg): tg = token group (32 tokens), cg = column group.
// Col ownership interleaved: wave owns cols cg*64 + 128*h + 0..63, h=0,1 -> every
// stage engages ALL 4 waves (v3 lesson), every weight byte read by exactly 2
// waves (vs v2's 4).  A-frags (af[16]) persistent in regs; z-build center
// term reuses af.  Logits per-wave over its 128 cols via yseg transpose +
// MFMA-diagonal; partials summed across cg-pair through part[].
//
// Stage stream: 48 stages x 16KB (3 dil x [8 M + 8 P]), ring of 2.  Consume
// sync = s_waitcnt vmcnt(0) + raw s_barrier (stage issued 1 slot ahead ->
// flight time = 1 full slot >> L2 latency; vmcnt+barrier = chip-wide ready).
// Issue after barrier overwrites the ring half consumed BEFORE that barrier.
// 16 MFMA per wave per slot.
//
// M-stage (r<8): ch=r>>2, ktp=r&3: cols ch*128+(0..127) x k ktp*64+(0..63).
// P-stage (r>=8): kt=r-8: out-cols g 0..255 x a kt*32+(0..31).
//
// LDS: xbuf 70x264 (36960) + bstage 2x16KB (32768) + yseg 4x16x72 (9216)
//      + part 2x64x3 f32 (1536) = 80480 B -> 2 blocks/CU.
// ---------------------------------------------------------------------------
__global__ __launch_bounds__(256, 2) void mega(const float* __restrict__ xf,
                                               const unsigned short* __restrict__ MtY,
                                               const unsigned short* __restrict__ PtZ,
                                               const float* __restrict__ bias,
                                               float* __restrict__ out) {
    __shared__ __align__(16) unsigned short xbuf[70 * 264];
    __shared__ __align__(16) unsigned short bstage[2 * 8192];
    __shared__ __align__(16) unsigned short yseg[4 * 16 * 72];
    __shared__ __align__(16) float part[2][64][3];

    const int tid = threadIdx.x;
    const int lane = tid & 63;
    const int wv = tid >> 6;
    const int q = lane >> 4;
    const int r16 = lane & 15;
    const int tg = wv >> 1;        // token group (32 tokens)
    const int cg = wv & 1;         // column group (interleaved 64-col chunks)
    const int t0 = blockIdx.x * 64;
    const int tokb = tg * 32;

    // staging source precompute (conflict swizzle: slot (tid&3) holds kc)
    const int c2t = tid >> 2;                       // 0..63
    const int kct = (tid & 3) ^ ((tid >> 3) & 3);
    const unsigned short* mB = MtY + (size_t)c2t * CC + kct * 8;
    const unsigned short* pB = PtZ + (size_t)c2t * NC + kct * 8;

    // Stage gs (0..47): dil i2 = gs>>4; r = gs&15.
    auto issue_stage = [&](int gs) {
        if (gs >= 48) return;
        unsigned short* dst = bstage + (gs & 1) * 8192 + tid * 8;
        const int i2 = gs >> 4;
        const int r = gs & 15;
        if (r < 8) {   // M: 128 cols (ch half) x 64 k
            const unsigned short* s0 =
                mB + (size_t)(i2 * 256 + (r >> 2) * 128) * CC + (r & 3) * 64;
            GL16(s0, dst);                                  // khalf0, cols 0..63
            GL16(s0 + (size_t)64 * CC, dst + 2048);         // khalf0, cols 64..127
            GL16(s0 + 32, dst + 4096);                      // khalf1, cols 0..63
            GL16(s0 + (size_t)64 * CC + 32, dst + 6144);    // khalf1, cols 64..127
        } else {       // P: 256 g x 32 a (kt = r-8)
            const unsigned short* s0 = pB + i2 * 256 + (r - 8) * 32;
            GL16(s0, dst);                                  // g 0..63
            GL16(s0 + (size_t)64 * NC, dst + 2048);         // g 64..127
            GL16(s0 + (size_t)128 * NC, dst + 4096);        // g 128..191
            GL16(s0 + (size_t)192 * NC, dst + 6144);        // g 192..255
        }
    };

    issue_stage(0);   // flies while x is staged

    // ---- stage x rows [t0-3, t0+67) fp32 -> bf16 LDS (clamped; masked later)
    for (int it = 0; it < 9; ++it) {
        int e = it * 256 + tid;          // 70 rows * 32 chunks = 2240
        if (e < 2240) {
            int rr = e >> 5, c = e & 31;
            int gr = t0 - 3 + rr;
            gr = gr < 0 ? 0 : (gr > MTOT - 1 ? MTOT - 1 : gr);
            const float* xp = xf + (size_t)gr * CC + c * 8;
            float4 a = *(const float4*)xp;
            float4 b = *(const float4*)(xp + 4);
            unsigned short p[8];
            p[0] = f2bf(a.x); p[1] = f2bf(a.y); p[2] = f2bf(a.z); p[3] = f2bf(a.w);
            p[4] = f2bf(b.x); p[5] = f2bf(b.y); p[6] = f2bf(b.z); p[7] = f2bf(b.w);
            *(float4*)(xbuf + rr * 264 + c * 8) = *(const float4*)p;
        }
    }
    __syncthreads();   // drains x loads AND stage 0 (one-time vmcnt(0))

    // persistent A-fragments: wave's 32 tokens x 256 k (2 tf x 8 kt)
    bf16x8 af[16];
#pragma unroll
    for (int tf = 0; tf < 2; ++tf)
#pragma unroll
        for (int kt = 0; kt < 8; ++kt)
            af[tf * 8 + kt] = *(const bf16x8*)(xbuf + (3 + tokb + tf * 16 + r16) * 264 +
                                               kt * 32 + q * 8);

    f32x4 oacc[16];   // [tf*8 + cf]: rows tokb+tf*16+q*4+r, col (cf>>2)*128+cg*64+(cf&3)*16+r16
#pragma unroll
    for (int j = 0; j < 16; ++j) oacc[j] = {0.f, 0.f, 0.f, 0.f};

    const int fragsw = q ^ ((r16 >> 1) & 3);   // fragment k-chunk swizzle

#pragma unroll 1
    for (int i = 0; i < 3; ++i) {
        const int dil = i + 1;
        f32x4 yacc[8];    // current ch-half: [tf*4 + cfl]
#pragma unroll
        for (int j = 0; j < 8; ++j) yacc[j] = {0.f, 0.f, 0.f, 0.f};
        float dg[2][3];   // logit partial accumulator (diag lanes)
        float wgt[2][3];  // softmax weights
        union ZA { unsigned int w[4]; bf16x8 v; };
        ZA za[2];

        // ================= M phase: 8 slots (ch-major) =================
#pragma unroll
        for (int sl = 0; sl < 8; ++sl) {
            asm volatile("s_waitcnt vmcnt(0)" ::: "memory");  // stage ready (this wave)
            __builtin_amdgcn_s_barrier();                     // -> ready chip-wide
            __builtin_amdgcn_sched_barrier(0);
            const unsigned short* bp = bstage + (sl & 1) * 8192;
            issue_stage(i * 16 + sl + 1);
#pragma unroll
            for (int h = 0; h < 2; ++h) {     // two 32-k halves of the stage
                bf16x8 bfr[4];
#pragma unroll
                for (int cfl = 0; cfl < 4; ++cfl)
                    bfr[cfl] = *(const bf16x8*)(bp + h * 4096 +
                                   ((cg * 64 + cfl * 16 + r16) * 4 + fragsw) * 8);
                __builtin_amdgcn_s_setprio(1);
#pragma unroll
                for (int tf = 0; tf < 2; ++tf)
#pragma unroll
                    for (int cfl = 0; cfl < 4; ++cfl)
                        yacc[tf * 4 + cfl] = __builtin_amdgcn_mfma_f32_16x16x32_bf16(
                            af[tf * 8 + (sl & 3) * 2 + h], bfr[cfl],
                            yacc[tf * 4 + cfl], 0, 0, 0);
                __builtin_amdgcn_s_setprio(0);
            }
            // logit pass when a ch-half completes (sl==3: ch0, sl==7: ch1)
            if (sl == 3 || sl == 7) {
                const int hh = sl >> 2;
                unsigned short* ys = yseg + wv * (16 * 72);
#pragma unroll
                for (int tf = 0; tf < 2; ++tf) {
#pragma unroll
                    for (int cfl = 0; cfl < 4; ++cfl)
#pragma unroll
                        for (int rr = 0; rr < 4; ++rr)
                            ys[(q * 4 + rr) * 72 + cfl * 16 + r16] =
                                f2bf(yacc[tf * 4 + cfl][rr]);
                    asm volatile("s_waitcnt lgkmcnt(0)" ::: "memory");
                    __builtin_amdgcn_sched_barrier(0);
                    bf16x8 ya0 = *(const bf16x8*)(ys + r16 * 72 + q * 8);
                    bf16x8 ya1 = *(const bf16x8*)(ys + r16 * 72 + 32 + q * 8);
                    f32x4 lc[3];
#pragma unroll
                    for (int j = 0; j < 3; ++j) lc[j] = {0.f, 0.f, 0.f, 0.f};
#pragma unroll
                    for (int j = 0; j < 3; ++j) {
                        const unsigned short* xr =
                            xbuf + (3 + tokb + tf * 16 + r16 + (j - 1) * dil) * 264 +
                            hh * 128 + cg * 64 + q * 8;
                        lc[j] = __builtin_amdgcn_mfma_f32_16x16x32_bf16(
                            ya0, *(const bf16x8*)xr, lc[j], 0, 0, 0);
                        lc[j] = __builtin_amdgcn_mfma_f32_16x16x32_bf16(
                            ya1, *(const bf16x8*)(xr + 32), lc[j], 0, 0, 0);
                    }
                    if (q == (r16 >> 2)) {     // diag lanes own token tokb+tf*16+r16
                        const int rs = r16 & 3;
#pragma unroll
                        for (int j = 0; j < 3; ++j) {
                            float v = rs == 0 ? lc[j][0] : rs == 1 ? lc[j][1]
                                    : rs == 2 ? lc[j][2] : lc[j][3];
                            dg[tf][j] = hh == 0 ? v : dg[tf][j] + v;
                        }
                    }
                }
                if (hh == 0) {
#pragma unroll
                    for (int j = 0; j < 8; ++j) yacc[j] = {0.f, 0.f, 0.f, 0.f};
                } else {
                    if (q == (r16 >> 2)) {
#pragma unroll
                        for (int tf = 0; tf < 2; ++tf) {
                            float* pp = &part[cg][tokb + tf * 16 + r16][0];
                            pp[0] = dg[tf][0]; pp[1] = dg[tf][1]; pp[2] = dg[tf][2];
                        }
                    }
                    asm volatile("s_waitcnt lgkmcnt(0)" ::: "memory");
                }
            }
        }

        // ================= P phase: 8 slots (kt 0..7) =================
#pragma unroll
        for (int sl = 0; sl < 8; ++sl) {
            asm volatile("s_waitcnt vmcnt(0)" ::: "memory");
            __builtin_amdgcn_s_barrier();
            __builtin_amdgcn_sched_barrier(0);
            const unsigned short* bp = bstage + (sl & 1) * 8192;
            issue_stage(i * 16 + 8 + sl + 1);
            if (sl == 0) {
                // combine cg partials + softmax (replicated; all lanes)
#pragma unroll
                for (int tf = 0; tf < 2; ++tf) {
                    const int tok = tokb + tf * 16 + r16;
                    float l0 = part[0][tok][0] + part[1][tok][0];
                    float l1 = part[0][tok][1] + part[1][tok][1];
                    float l2 = part[0][tok][2] + part[1][tok][2];
                    const int ns = (t0 + tok) & (NN - 1);
                    const bool vlo = ns >= dil;
                    const bool vhi = ns + dil < NN;
                    l0 = vlo ? l0 : 0.f;    // zero-logit padding (matches reference)
                    l2 = vhi ? l2 : 0.f;
                    float mx = fmaxf(l0, fmaxf(l1, l2));
                    float e0 = __expf(l0 - mx), e1 = __expf(l1 - mx), e2 = __expf(l2 - mx);
                    float inv = 1.0f / (e0 + e1 + e2);
                    wgt[tf][0] = vlo ? e0 * inv : 0.f;
                    wgt[tf][1] = e1 * inv;
                    wgt[tf][2] = vhi ? e2 * inv : 0.f;
                }
            }
            // build z A-frags for this k-chunk (center term from persistent af)
#pragma unroll
            for (int tf = 0; tf < 2; ++tf) {
                const unsigned short* xr1 =
                    xbuf + (3 + tokb + tf * 16 + r16) * 264 + sl * 32 + q * 8;
                bf16x8 a0 = *(const bf16x8*)(xr1 - dil * 264);
                bf16x8 a2 = *(const bf16x8*)(xr1 + dil * 264);
                const unsigned short* u0 = (const unsigned short*)&a0;
                const unsigned short* u1 = (const unsigned short*)&af[tf * 8 + sl];
                const unsigned short* u2 = (const unsigned short*)&a2;
                const float w0 = wgt[tf][0], w1 = wgt[tf][1], w2 = wgt[tf][2];
#pragma unroll
                for (int e2i = 0; e2i < 4; ++e2i) {
                    float zl = w0 * bf2f(u0[e2i * 2]) + w1 * bf2f(u1[e2i * 2]) +
                               w2 * bf2f(u2[e2i * 2]);
                    float zh = w0 * bf2f(u0[e2i * 2 + 1]) + w1 * bf2f(u1[e2i * 2 + 1]) +
                               w2 * bf2f(u2[e2i * 2 + 1]);
                    asm("v_cvt_pk_bf16_f32 %0, %1, %2"
                        : "=v"(za[tf].w[e2i]) : "v"(zl), "v"(zh));
                }
            }
            __builtin_amdgcn_s_setprio(1);
#pragma unroll
            for (int ch = 0; ch < 2; ++ch)
#pragma unroll
                for (int cfl = 0; cfl < 4; ++cfl) {
                    bf16x8 b = *(const bf16x8*)(bp + (ch * 2 + cg) * 2048 +
                                    ((cfl * 16 + r16) * 4 + fragsw) * 8);
#pragma unroll
                    for (int tf = 0; tf < 2; ++tf)
                        oacc[tf * 8 + ch * 4 + cfl] =
                            __builtin_amdgcn_mfma_f32_16x16x32_bf16(
                                za[tf].v, b, oacc[tf * 8 + ch * 4 + cfl], 0, 0, 0);
                }
            __builtin_amdgcn_s_setprio(0);
        }
    }

    // ================= Epilogue: out = oacc + bias =================
#pragma unroll
    for (int tf = 0; tf < 2; ++tf)
#pragma unroll
        for (int cf = 0; cf < 8; ++cf) {
            const int gc = (cf >> 2) * 128 + cg * 64 + (cf & 3) * 16 + r16;
            float bc = bias[gc];
            f32x4 v = oacc[tf * 8 + cf];
#pragma unroll
            for (int r = 0; r < 4; ++r)
                out[(size_t)(t0 + tokb + tf * 16 + q * 4 + r) * CC + gc] = v[r] + bc;
        }
}

// ---------------------------------------------------------------------------
extern "C" void kernel_launch(void* const* d_in, const int* in_sizes, int n_in,
                              void* d_out, int out_size, void* d_ws, size_t ws_size,
                              hipStream_t stream) {
    const float* x = (const float*)d_in[0];      // (16, 4096, 256)
    const float* Wqkv = (const float*)d_in[1];   // (3, 256, 768)
    const float* Wproj = (const float*)d_in[2];  // (256, 256)
    const float* bproj = (const float*)d_in[3];  // (256,)
    float* out = (float*)d_out;                  // (16, 4096, 256)

    unsigned short* Wqb = (unsigned short*)d_ws;           // 3*256*256
    unsigned short* Wkb = Wqb + (size_t)3 * CC * CC;
    unsigned short* Wvs = Wkb + (size_t)3 * CC * CC;       // (768,256): [(i,a)][c]
    unsigned short* WpT = Wvs + (size_t)3 * CC * CC;       // (256,256): [g][c]
    unsigned short* MtY = WpT + (size_t)CC * CC;           // (768,256): [(i,b)][a]
    unsigned short* PtZ = MtY + (size_t)NC * CC;           // (256,768): [g][(i,a)]

    conv_all<<<(3 * CC * NC + CC * CC) / 256, 256, 0, stream>>>(
        Wqkv, Wproj, Wqb, Wkb, Wvs, WpT);
    wgemm<<<dim3(6, 2, 4), 256, 0, stream>>>(Wqb, Wkb, Wvs, WpT, MtY, PtZ);
    mega<<<MTOT / 64, 256, 0, stream>>>(x, MtY, PtZ, bproj, out);
}